// Round 3
// baseline (2621.629 us; speedup 1.0000x reference)
//
#include <hip/hip_runtime.h>

typedef unsigned short u16;
typedef unsigned int   u32;
typedef __bf16  bf16x8 __attribute__((ext_vector_type(8)));
typedef float   f32x4  __attribute__((ext_vector_type(4)));

#define DEV __device__ __forceinline__

DEV float bf2f(u16 u){ union{u32 i; float f;} x; x.i = ((u32)u)<<16; return x.f; }
DEV u16 f2bf(float f){ u32 x = __float_as_uint(f); u32 r = (x + 0x7FFFu + ((x>>16)&1u))>>16; return (u16)r; }

DEV f32x4 mfma16(bf16x8 a, bf16x8 b, f32x4 c){
  return __builtin_amdgcn_mfma_f32_16x16x32_bf16(a,b,c,0,0,0);
}
DEV void gload_lds16(const void* g, void* l){
  __builtin_amdgcn_global_load_lds((const __attribute__((address_space(1))) void*)g,
                                   (__attribute__((address_space(3))) void*)l, 16, 0, 0);
}

// ---------------------------------------------------------------- weights: f32 [K][N] -> bf16 [N][K]
__global__ __launch_bounds__(256) void transpose_w(const float* __restrict__ W, u16* __restrict__ Wt,
                                                   int K, int N){
  __shared__ float tile[32][33];
  const int n0 = blockIdx.x*32, k0 = blockIdx.y*32;
  const int tx = threadIdx.x & 31, ty = threadIdx.x >> 5;
  #pragma unroll
  for (int i=0;i<4;++i) tile[ty+8*i][tx] = W[(size_t)(k0+ty+8*i)*N + n0+tx];
  __syncthreads();
  #pragma unroll
  for (int i=0;i<4;++i) Wt[(size_t)(n0+ty+8*i)*K + k0+tx] = f2bf(tile[tx][ty+8*i]);
}

// ---------------------------------------------------------------- LayerNorm: f32 row -> bf16 row (D=1152)
__global__ __launch_bounds__(256) void ln_k(const float* __restrict__ x, const float* __restrict__ gg,
                                            const float* __restrict__ bb, u16* __restrict__ o){
  const int row = blockIdx.x, t = threadIdx.x;
  const float4* xr = (const float4*)(x + (size_t)row*1152);
  float4 v1 = xr[t];
  float s  = v1.x+v1.y+v1.z+v1.w;
  float ss = v1.x*v1.x+v1.y*v1.y+v1.z*v1.z+v1.w*v1.w;
  float4 v2 = {0,0,0,0};
  if (t < 32){ v2 = xr[256+t]; s += v2.x+v2.y+v2.z+v2.w; ss += v2.x*v2.x+v2.y*v2.y+v2.z*v2.z+v2.w*v2.w; }
  #pragma unroll
  for (int off=32; off; off>>=1){ s += __shfl_xor(s,off); ss += __shfl_xor(ss,off); }
  __shared__ float sm[8];
  if ((t&63)==0){ sm[t>>6]=s; sm[4+(t>>6)]=ss; }
  __syncthreads();
  s  = sm[0]+sm[1]+sm[2]+sm[3];
  ss = sm[4]+sm[5]+sm[6]+sm[7];
  const float mu = s*(1.f/1152.f);
  const float var = ss*(1.f/1152.f) - mu*mu;
  const float rs = rsqrtf(var + 1e-5f);
  const float4* g4 = (const float4*)gg; const float4* b4 = (const float4*)bb;
  ushort4* orow = (ushort4*)(o + (size_t)row*1152);
  {
    float4 gv = g4[t], bv = b4[t];
    ushort4 u; u.x=f2bf((v1.x-mu)*rs*gv.x+bv.x); u.y=f2bf((v1.y-mu)*rs*gv.y+bv.y);
               u.z=f2bf((v1.z-mu)*rs*gv.z+bv.z); u.w=f2bf((v1.w-mu)*rs*gv.w+bv.w);
    orow[t] = u;
  }
  if (t < 32){
    float4 gv = g4[256+t], bv = b4[256+t];
    ushort4 u; u.x=f2bf((v2.x-mu)*rs*gv.x+bv.x); u.y=f2bf((v2.y-mu)*rs*gv.y+bv.y);
               u.z=f2bf((v2.z-mu)*rs*gv.z+bv.z); u.w=f2bf((v2.w-mu)*rs*gv.w+bv.w);
    orow[256+t] = u;
  }
}

// ---------------------------------------------------------------- encoder f32 -> bf16, pad 616->640 rows
__global__ void enc_conv(const float* __restrict__ e, u16* __restrict__ ne){
  int i = blockIdx.x*256 + threadIdx.x;           // over 640*288 ushort4-groups
  if (i >= 640*288) return;
  int row = i / 288;
  ushort4 u = {0,0,0,0};
  if (row < 616){ float4 v = ((const float4*)e)[i];
    u.x=f2bf(v.x); u.y=f2bf(v.y); u.z=f2bf(v.z); u.w=f2bf(v.w); }
  ((ushort4*)ne)[i] = u;
}

// ---------------------------------------------------------------- min/max reduce + quantize (bf16 tensors)
__global__ __launch_bounds__(256) void minmax_part(const ushort4* __restrict__ x, int n4, float2* __restrict__ part){
  float mn = 3e38f, mx = -3e38f;
  for (int i = blockIdx.x*256 + threadIdx.x; i < n4; i += gridDim.x*256){
    ushort4 u = x[i];
    float a=bf2f(u.x), b=bf2f(u.y), c=bf2f(u.z), d=bf2f(u.w);
    mn = fminf(mn, fminf(fminf(a,b),fminf(c,d)));
    mx = fmaxf(mx, fmaxf(fmaxf(a,b),fmaxf(c,d)));
  }
  #pragma unroll
  for (int off=32; off; off>>=1){ mn=fminf(mn,__shfl_xor(mn,off)); mx=fmaxf(mx,__shfl_xor(mx,off)); }
  __shared__ float smn[4], smx[4];
  if ((threadIdx.x&63)==0){ smn[threadIdx.x>>6]=mn; smx[threadIdx.x>>6]=mx; }
  __syncthreads();
  if (threadIdx.x==0){
    mn = fminf(fminf(smn[0],smn[1]),fminf(smn[2],smn[3]));
    mx = fmaxf(fmaxf(smx[0],smx[1]),fmaxf(smx[2],smx[3]));
    part[blockIdx.x] = make_float2(mn,mx);
  }
}
__global__ __launch_bounds__(256) void minmax_final(const float2* __restrict__ part, int np, float* __restrict__ prm){
  float mn = 3e38f, mx = -3e38f;
  for (int i = threadIdx.x; i < np; i += 256){ mn=fminf(mn,part[i].x); mx=fmaxf(mx,part[i].y); }
  #pragma unroll
  for (int off=32; off; off>>=1){ mn=fminf(mn,__shfl_xor(mn,off)); mx=fmaxf(mx,__shfl_xor(mx,off)); }
  __shared__ float smn[4], smx[4];
  if ((threadIdx.x&63)==0){ smn[threadIdx.x>>6]=mn; smx[threadIdx.x>>6]=mx; }
  __syncthreads();
  if (threadIdx.x==0){
    mn = fminf(fminf(smn[0],smn[1]),fminf(smn[2],smn[3]));
    mx = fmaxf(fmaxf(smx[0],smx[1]),fmaxf(smx[2],smx[3]));
    float d = (mx-mn)*(1.f/255.f);
    if (!(d > 0.f)) d = 1e-8f;
    prm[0] = d; prm[1] = rintf(-mn/d);
  }
}
__global__ __launch_bounds__(256) void quant_ip(ushort4* __restrict__ x, int n4, const float* __restrict__ prm){
  const float d = prm[0], zp = prm[1];
  for (int i = blockIdx.x*256 + threadIdx.x; i < n4; i += gridDim.x*256){
    ushort4 u = x[i];
    float a=bf2f(u.x), b=bf2f(u.y), c=bf2f(u.z), e=bf2f(u.w);
    a = (fminf(fmaxf(rintf(a/d)+zp,0.f),255.f)-zp)*d;
    b = (fminf(fmaxf(rintf(b/d)+zp,0.f),255.f)-zp)*d;
    c = (fminf(fmaxf(rintf(c/d)+zp,0.f),255.f)-zp)*d;
    e = (fminf(fmaxf(rintf(e/d)+zp,0.f),255.f)-zp)*d;
    u.x=f2bf(a); u.y=f2bf(b); u.z=f2bf(c); u.w=f2bf(e);
    x[i]=u;
  }
}

// ---------------------------------------------------------------- min(l) -> delta_p
__global__ __launch_bounds__(256) void lmin_part(const float4* __restrict__ l4, int n4, float* __restrict__ part){
  float mn = 3e38f;
  for (int i = blockIdx.x*256+threadIdx.x; i<n4; i+=gridDim.x*256){
    float4 v = l4[i];
    mn = fminf(mn, fminf(fminf(v.x,v.y), fminf(v.z,v.w)));
  }
  #pragma unroll
  for (int off=32; off; off>>=1) mn = fminf(mn, __shfl_xor(mn, off));
  __shared__ float sm[4];
  if ((threadIdx.x&63)==0) sm[threadIdx.x>>6] = mn;
  __syncthreads();
  if (threadIdx.x==0) part[blockIdx.x] = fminf(fminf(sm[0],sm[1]),fminf(sm[2],sm[3]));
}
__global__ __launch_bounds__(256) void lmin_final(const float* __restrict__ part, int np, float* __restrict__ prm){
  float mn = 3e38f;
  for (int i = threadIdx.x; i<np; i+=256) mn = fminf(mn, part[i]);
  #pragma unroll
  for (int off=32; off; off>>=1) mn = fminf(mn, __shfl_xor(mn, off));
  __shared__ float sm[4];
  if ((threadIdx.x&63)==0) sm[threadIdx.x>>6] = mn;
  __syncthreads();
  if (threadIdx.x==0){
    mn = fminf(fminf(sm[0],sm[1]),fminf(sm[2],sm[3]));
    float dp = (1.f/mn)*(1.f/255.f);
    prm[0] = dp; prm[1] = 1.f/dp;
  }
}

// ---------------------------------------------------------------- GEMM: C[M,N] = A[M,K](bf16) @ Bt[N,K]^T(bf16)
// EPI 0: C bf16 store ; 1: C bf16 store + bias ; 2: float C += acc + bias
template<int EPI>
__global__ __launch_bounds__(256, 2)
void gemm_bt(const u16* __restrict__ A, const u16* __restrict__ Bt, void* __restrict__ C,
             const float* __restrict__ bias, int K, int ldc){
  __shared__ u16 As[128*64];
  __shared__ u16 Bs[128*64];
  const int t = threadIdx.x;
  const int lane = t & 63, w = t >> 6;
  const int wm = w >> 1, wn = w & 1;
  const int l15 = lane & 15, r16 = (lane >> 4) * 8;
  const int m0 = blockIdx.y * 128, n0 = blockIdx.x * 128;
  const size_t ldaB = (size_t)K * 2;

  f32x4 acc[4][4];
  #pragma unroll
  for (int i=0;i<4;++i)
    #pragma unroll
    for (int j=0;j<4;++j) acc[i][j] = (f32x4){0.f,0.f,0.f,0.f};

  const char* gA = (const char*)A + (size_t)m0 * ldaB;
  const char* gB = (const char*)Bt + (size_t)n0 * ldaB;

  for (int kt = 0; kt < K; kt += 64){
    const size_t kb = (size_t)kt * 2;
    #pragma unroll
    for (int r = 0; r < 4; ++r){
      int li  = r*256 + t;
      int row = li >> 3;
      int cb  = (li & 7) << 4;
      gload_lds16(gA + (size_t)row*ldaB + kb + cb, (char*)As + r*4096 + w*1024);
      gload_lds16(gB + (size_t)row*ldaB + kb + cb, (char*)Bs + r*4096 + w*1024);
    }
    __syncthreads();
    #pragma unroll
    for (int kc = 0; kc < 2; ++kc){
      bf16x8 af[4], bfv[4];
      #pragma unroll
      for (int i=0;i<4;++i) af[i]  = *(const bf16x8*)(As + (wm*64 + i*16 + l15)*64 + kc*32 + r16);
      #pragma unroll
      for (int j=0;j<4;++j) bfv[j] = *(const bf16x8*)(Bs + (wn*64 + j*16 + l15)*64 + kc*32 + r16);
      #pragma unroll
      for (int i=0;i<4;++i)
        #pragma unroll
        for (int j=0;j<4;++j)
          acc[i][j] = mfma16(af[i], bfv[j], acc[i][j]);
    }
    __syncthreads();
  }

  #pragma unroll
  for (int i=0;i<4;++i){
    const int rowb = m0 + wm*64 + i*16 + (lane>>4)*4;
    #pragma unroll
    for (int j=0;j<4;++j){
      const int col = n0 + wn*64 + j*16 + l15;
      float bv = 0.f;
      if (EPI >= 1) bv = bias[col];
      #pragma unroll
      for (int r=0;r<4;++r){
        float v = acc[i][j][r] + bv;
        if (EPI == 2){
          float* H = (float*)C;
          H[(size_t)(rowb + r)*ldc + col] += v;
        } else {
          ((u16*)C)[(size_t)(rowb + r)*ldc + col] = f2bf(v);
        }
      }
    }
  }
}

// ---------------------------------------------------------------- attention passes
// PASSB=0: compute per-row (m, l).  PASSB=1: recompute scores, quantize probs, PV -> out.
template<int PASSB>
__global__ __launch_bounds__(256)
void attn_pass(const u16* __restrict__ qh, const u16* __restrict__ kh, const u16* __restrict__ vh,
               float* __restrict__ mbuf, float* __restrict__ lbuf,
               const float* __restrict__ prmP, u16* __restrict__ outp,
               int SK, int SKT, int kvRowsPerB){
  __shared__ u16 smem[PASSB ? (64*96*2 + 80*64 + 64*64) : (64*96*2)];
  u16* qs  = smem;             // [64][96]
  u16* ks  = qs + 64*96;       // [64][96]
  u16* vts = ks + 64*96;       // [80][64]  (PASSB)
  u16* ps  = vts + 80*64;      // [64][64]  (PASSB)

  const int t = threadIdx.x;
  const int lane = t & 63, w = t >> 6;
  const int l15 = lane & 15, rg = lane >> 4;
  const int qt = blockIdx.x, bh = blockIdx.y;
  const int b = bh >> 4, h = bh & 15;
  const int q0 = qt * 64;
  const float scale = 0.11785113019775793f;   // 1/sqrt(72)

  const char* qbase = (const char*)qh + ((size_t)(b*1024 + q0)*1152 + h*72)*2;
  const char* kbase = (const char*)kh + ((size_t)((size_t)b*kvRowsPerB)*1152 + h*72)*2;
  const char* vbase = (const char*)vh + ((size_t)((size_t)b*kvRowsPerB)*1152 + h*72)*2;

  for (int li = t; li < 64*48; li += 256){     // stage Q tile (zero-pad head dim 72->96)
    int row = li/48, cu = li - row*48;
    u32 val = 0;
    if (cu < 36) val = *(const u32*)(qbase + (size_t)row*2304 + cu*4);
    ((u32*)qs)[row*48+cu] = val;
  }
  if (PASSB){
    for (int li = t; li < 256; li += 256)      // zero vt pad rows 72..79
      ((u32*)(vts + 72*64))[li] = 0;
  }

  float mr[4], lr[4], invl[4];
  float dp = 0.f, invdp = 0.f;
  if (PASSB){
    dp = prmP[0]; invdp = prmP[1];
    #pragma unroll
    for (int r=0;r<4;++r){
      int row = q0 + w*16 + rg*4 + r;
      mr[r]   = mbuf[(size_t)bh*1024 + row];
      invl[r] = 1.f / lbuf[(size_t)bh*1024 + row];
    }
  } else {
    #pragma unroll
    for (int r=0;r<4;++r){ mr[r] = -1e30f; lr[r] = 0.f; }
  }

  f32x4 oacc[5];
  if (PASSB){
    #pragma unroll
    for (int cb=0;cb<5;++cb) oacc[cb] = (f32x4){0.f,0.f,0.f,0.f};
  }

  for (int kt = 0; kt < SKT; ++kt){
    if (kt) __syncthreads();
    for (int li = t; li < 64*48; li += 256){   // stage K tile (guard rows >= SK -> 0)
      int row = li/48, cu = li - row*48;
      int krow = kt*64 + row;
      u32 val = 0;
      if (cu < 36 && krow < SK) val = *(const u32*)(kbase + (size_t)krow*2304 + cu*4);
      ((u32*)ks)[row*48+cu] = val;
    }
    if (PASSB){
      for (int li = t; li < 64*36; li += 256){ // stage V transposed [hd][k] (guard rows >= SK -> 0)
        int kr = li/36, hu = li - kr*36;
        int krow = kt*64 + kr;
        u32 val = 0;
        if (krow < SK) val = *(const u32*)(vbase + (size_t)krow*2304 + hu*4);
        vts[(hu*2)*64 + kr]   = (u16)(val & 0xffffu);
        vts[(hu*2+1)*64 + kr] = (u16)(val >> 16);
      }
    }
    __syncthreads();

    f32x4 acc[4];
    #pragma unroll
    for (int cb=0;cb<4;++cb) acc[cb] = (f32x4){0.f,0.f,0.f,0.f};
    #pragma unroll
    for (int kc=0;kc<3;++kc){
      bf16x8 aq = *(const bf16x8*)(qs + (w*16 + l15)*96 + kc*32 + rg*8);
      #pragma unroll
      for (int cb=0;cb<4;++cb){
        bf16x8 bk = *(const bf16x8*)(ks + (cb*16 + l15)*96 + kc*32 + rg*8);
        acc[cb] = mfma16(aq, bk, acc[cb]);
      }
    }
    float s[4][4];
    #pragma unroll
    for (int cb=0;cb<4;++cb){
      const int col = kt*64 + cb*16 + l15;
      const bool valid = col < SK;
      #pragma unroll
      for (int r=0;r<4;++r){
        float x = acc[cb][r]*scale;
        s[cb][r] = valid ? x : -1e30f;
      }
    }
    if (!PASSB){
      #pragma unroll
      for (int r=0;r<4;++r){
        float mt = fmaxf(fmaxf(s[0][r],s[1][r]), fmaxf(s[2][r],s[3][r]));
        #pragma unroll
        for (int off=1; off<16; off<<=1) mt = fmaxf(mt, __shfl_xor(mt, off));
        float mn = fmaxf(mr[r], mt);
        float sum = __expf(s[0][r]-mn)+__expf(s[1][r]-mn)+__expf(s[2][r]-mn)+__expf(s[3][r]-mn);
        #pragma unroll
        for (int off=1; off<16; off<<=1) sum += __shfl_xor(sum, off);
        lr[r] = lr[r]*__expf(mr[r]-mn) + sum;
        mr[r] = mn;
      }
    } else {
      #pragma unroll
      for (int cb=0;cb<4;++cb){
        #pragma unroll
        for (int r=0;r<4;++r){
          float p  = __expf(s[cb][r]-mr[r]) * invl[r];
          float pq = fminf(rintf(p*invdp), 255.f) * dp;
          ps[(w*16 + rg*4 + r)*64 + cb*16 + l15] = f2bf(pq);
        }
      }
      __syncthreads();
      #pragma unroll
      for (int kc=0;kc<2;++kc){
        bf16x8 ap = *(const bf16x8*)(ps + (w*16 + l15)*64 + kc*32 + rg*8);
        #pragma unroll
        for (int cb=0;cb<5;++cb){
          bf16x8 bv = *(const bf16x8*)(vts + (cb*16 + l15)*64 + kc*32 + rg*8);
          oacc[cb] = mfma16(ap, bv, oacc[cb]);
        }
      }
    }
  }

  if (!PASSB){
    if (l15 == 0){
      #pragma unroll
      for (int r=0;r<4;++r){
        int row = q0 + w*16 + rg*4 + r;
        mbuf[(size_t)bh*1024 + row] = mr[r];
        lbuf[(size_t)bh*1024 + row] = lr[r];
      }
    }
  } else {
    #pragma unroll
    for (int cb=0;cb<5;++cb){
      int hd = cb*16 + l15;
      if (hd < 72){
        #pragma unroll
        for (int r=0;r<4;++r){
          int row = q0 + w*16 + rg*4 + r;
          outp[((size_t)(b*1024 + row))*1152 + h*72 + hd] = f2bf(oacc[cb][r]);
        }
      }
    }
  }
}

// ---------------------------------------------------------------- GEGLU elementwise
__global__ __launch_bounds__(256) void geglu_k(const u16* __restrict__ proj, u16* __restrict__ out, int rows){
  const int total = rows*1152;                 // ushort4 groups (4608/4 per row)
  for (int i = blockIdx.x*256+threadIdx.x; i < total; i += gridDim.x*256){
    int row = i / 1152, c4 = i - row*1152;
    ushort4 ua = ((const ushort4*)(proj + (size_t)row*9216))[c4];
    ushort4 ug = ((const ushort4*)(proj + (size_t)row*9216 + 4608))[c4];
    float a0=bf2f(ua.x), a1=bf2f(ua.y), a2=bf2f(ua.z), a3=bf2f(ua.w);
    float g0=bf2f(ug.x), g1=bf2f(ug.y), g2=bf2f(ug.z), g3=bf2f(ug.w);
    const float c = 0.70710678118654752f;
    g0 = 0.5f*g0*(1.f+erff(g0*c)); g1 = 0.5f*g1*(1.f+erff(g1*c));
    g2 = 0.5f*g2*(1.f+erff(g2*c)); g3 = 0.5f*g3*(1.f+erff(g3*c));
    ushort4 u; u.x=f2bf(a0*g0); u.y=f2bf(a1*g1); u.z=f2bf(a2*g2); u.w=f2bf(a3*g3);
    ((ushort4*)(out + (size_t)row*4608))[c4] = u;
  }
}

// ================================================================ launcher
extern "C" void kernel_launch(void* const* d_in, const int* in_sizes, int n_in,
                              void* d_out, int out_size, void* d_ws, size_t ws_size,
                              hipStream_t stream){
  const float* hidden = (const float*)d_in[0];
  const float* enc    = (const float*)d_in[1];
  const float* ln1g = (const float*)d_in[2];  const float* ln1b = (const float*)d_in[3];
  const float* Wq1 = (const float*)d_in[4];   const float* Wk1 = (const float*)d_in[5];
  const float* Wv1 = (const float*)d_in[6];   const float* Wo1 = (const float*)d_in[7];
  const float* bo1 = (const float*)d_in[8];
  const float* ln2g = (const float*)d_in[9];  const float* ln2b = (const float*)d_in[10];
  const float* Wq2 = (const float*)d_in[11];  const float* Wk2 = (const float*)d_in[12];
  const float* Wv2 = (const float*)d_in[13];  const float* Wo2 = (const float*)d_in[14];
  const float* bo2 = (const float*)d_in[15];
  const float* ln3g = (const float*)d_in[16]; const float* ln3b = (const float*)d_in[17];
  const float* Wff1 = (const float*)d_in[18]; const float* bff1 = (const float*)d_in[19];
  const float* Wff2 = (const float*)d_in[20]; const float* bff2 = (const float*)d_in[21];

  // d_out IS the f32 residual accumulator Hf: [8192][1152] f32 = 37,748,736 B
  float* Hf = (float*)d_out;

  char* ws = (char*)d_ws;
  // ---- compact layout, high-water ~80.7 MB ----
  u16*  Nb   = (u16*)(ws + 0);                //  18,874,368  bf16 [8192][1152]
  u16*  Qb   = (u16*)(ws + 18874368);         //  18,874,368
  u16*  Kb   = (u16*)(ws + 37748736);         //  18,874,368
  u16*  Vb   = (u16*)(ws + 56623104);         //  18,874,368  (ends 75,497,472)
  u16*  NE   = (u16*)(ws + 75497472);         //   1,474,560  bf16 [640][1152]
  float* Mb  = (float*)(ws + 76972032);       //     524,288
  float* Lb  = (float*)(ws + 77496320);       //     524,288
  float2* Part = (float2*)(ws + 78020608);    //      16,384
  float* PartF = (float*)(ws + 78020608);
  float* Prm = (float*)(ws + 78036992);       //         256
  u16*  Wsl  = (u16*)(ws + 78037248);         //   2,654,208  rotating attn weight slot (ends 80,691,456)
  // FF-phase overlay (Qb/Kb/Vb/NE/Mb/Lb/Part/Prm/Wsl all dead by then)
  u16*  Wff1t = (u16*)(ws + 18874368);        //  21,233,664
  u16*  Wff2t = (u16*)(ws + 40108032);        //  10,616,832
  u16*  PROJ  = (u16*)(ws + 50724864);        //  18,874,368  bf16 [1024][9216]
  u16*  GEG   = (u16*)(ws + 69599232);        //   9,437,184  bf16 [1024][4608] (ends 79,036,416)

  const int NT = 8192;                // tokens
  const int NQ4 = NT*1152/4;          // 2,359,296 ushort4 in a [8192,1152] bf16 buffer

  hipMemcpyAsync(Hf, hidden, (size_t)NT*1152*4, hipMemcpyDeviceToDevice, stream);
  enc_conv<<<720,256,0,stream>>>(enc, NE);

  // ---------------- self-attention ----------------
  ln_k<<<NT,256,0,stream>>>(Hf, ln1g, ln1b, Nb);
  transpose_w<<<dim3(36,36),256,0,stream>>>(Wq1, Wsl, 1152, 1152);
  gemm_bt<0><<<dim3(9,64),256,0,stream>>>(Nb, Wsl, Qb, nullptr, 1152, 1152);
  transpose_w<<<dim3(36,36),256,0,stream>>>(Wk1, Wsl, 1152, 1152);
  gemm_bt<0><<<dim3(9,64),256,0,stream>>>(Nb, Wsl, Kb, nullptr, 1152, 1152);
  transpose_w<<<dim3(36,36),256,0,stream>>>(Wv1, Wsl, 1152, 1152);
  gemm_bt<0><<<dim3(9,64),256,0,stream>>>(Nb, Wsl, Vb, nullptr, 1152, 1152);

  minmax_part<<<1024,256,0,stream>>>((ushort4*)Qb, NQ4, Part);
  minmax_final<<<1,256,0,stream>>>(Part, 1024, Prm+0);
  quant_ip<<<2048,256,0,stream>>>((ushort4*)Qb, NQ4, Prm+0);
  minmax_part<<<1024,256,0,stream>>>((ushort4*)Kb, NQ4, Part);
  minmax_final<<<1,256,0,stream>>>(Part, 1024, Prm+2);
  quant_ip<<<2048,256,0,stream>>>((ushort4*)Kb, NQ4, Prm+2);
  minmax_part<<<1024,256,0,stream>>>((ushort4*)Vb, NQ4, Part);
  minmax_final<<<1,256,0,stream>>>(Part, 1024, Prm+4);
  quant_ip<<<2048,256,0,stream>>>((ushort4*)Vb, NQ4, Prm+4);

  attn_pass<0><<<dim3(16,128),256,0,stream>>>(Qb,Kb,nullptr, Mb,Lb, nullptr,nullptr, 1024,16,1024);
  lmin_part<<<64,256,0,stream>>>((const float4*)Lb, 32768, PartF);
  lmin_final<<<1,256,0,stream>>>(PartF, 64, Prm+6);
  attn_pass<1><<<dim3(16,128),256,0,stream>>>(Qb,Kb,Vb, Mb,Lb, Prm+6, Nb, 1024,16,1024);
  transpose_w<<<dim3(36,36),256,0,stream>>>(Wo1, Wsl, 1152, 1152);
  gemm_bt<2><<<dim3(9,64),256,0,stream>>>(Nb, Wsl, Hf, bo1, 1152, 1152);

  // ---------------- cross-attention ----------------
  ln_k<<<NT,256,0,stream>>>(Hf, ln2g, ln2b, Nb);
  transpose_w<<<dim3(36,36),256,0,stream>>>(Wq2, Wsl, 1152, 1152);
  gemm_bt<0><<<dim3(9,64),256,0,stream>>>(Nb, Wsl, Qb, nullptr, 1152, 1152);
  transpose_w<<<dim3(36,36),256,0,stream>>>(Wk2, Wsl, 1152, 1152);
  gemm_bt<0><<<dim3(9,5),256,0,stream>>>(NE, Wsl, Kb, nullptr, 1152, 1152);
  transpose_w<<<dim3(36,36),256,0,stream>>>(Wv2, Wsl, 1152, 1152);
  gemm_bt<0><<<dim3(9,5),256,0,stream>>>(NE, Wsl, Vb, nullptr, 1152, 1152);

  const int NK4r = 616*1152/4;  // real encoder rows only for calibration
  const int NK4c = 640*1152/4;  // quantize incl. zero pad rows (0 -> 0)
  minmax_part<<<1024,256,0,stream>>>((ushort4*)Qb, NQ4, Part);
  minmax_final<<<1,256,0,stream>>>(Part, 1024, Prm+0);
  quant_ip<<<2048,256,0,stream>>>((ushort4*)Qb, NQ4, Prm+0);
  minmax_part<<<512,256,0,stream>>>((ushort4*)Kb, NK4r, Part);
  minmax_final<<<1,256,0,stream>>>(Part, 512, Prm+2);
  quant_ip<<<512,256,0,stream>>>((ushort4*)Kb, NK4c, Prm+2);
  minmax_part<<<512,256,0,stream>>>((ushort4*)Vb, NK4r, Part);
  minmax_final<<<1,256,0,stream>>>(Part, 512, Prm+4);
  quant_ip<<<512,256,0,stream>>>((ushort4*)Vb, NK4c, Prm+4);

  attn_pass<0><<<dim3(16,128),256,0,stream>>>(Qb,Kb,nullptr, Mb,Lb, nullptr,nullptr, 77,2,77);
  lmin_part<<<64,256,0,stream>>>((const float4*)Lb, 32768, PartF);
  lmin_final<<<1,256,0,stream>>>(PartF, 64, Prm+6);
  attn_pass<1><<<dim3(16,128),256,0,stream>>>(Qb,Kb,Vb, Mb,Lb, Prm+6, Nb, 77,2,77);
  transpose_w<<<dim3(36,36),256,0,stream>>>(Wo2, Wsl, 1152, 1152);
  gemm_bt<2><<<dim3(9,64),256,0,stream>>>(Nb, Wsl, Hf, bo2, 1152, 1152);

  // ---------------- feed-forward (GEGLU), 8 chunks of 1024 rows ----------------
  ln_k<<<NT,256,0,stream>>>(Hf, ln3g, ln3b, Nb);
  transpose_w<<<dim3(288,36),256,0,stream>>>(Wff1, Wff1t, 1152, 9216);
  transpose_w<<<dim3(36,144),256,0,stream>>>(Wff2, Wff2t, 4608, 1152);
  for (int c = 0; c < 8; ++c){
    gemm_bt<1><<<dim3(72,8),256,0,stream>>>(Nb + (size_t)c*1024*1152, Wff1t, PROJ, bff1, 1152, 9216);
    geglu_k<<<1024,256,0,stream>>>(PROJ, GEG, 1024);
    gemm_bt<2><<<dim3(9,8),256,0,stream>>>(GEG, Wff2t, Hf + (size_t)c*1024*1152, bff2, 4608, 1152);
  }
}

// Round 4
// 2545.340 us; speedup vs baseline: 1.0300x; 1.0300x over previous
//
#include <hip/hip_runtime.h>

typedef unsigned short u16;
typedef unsigned int   u32;
typedef __bf16  bf16x8 __attribute__((ext_vector_type(8)));
typedef float   f32x4  __attribute__((ext_vector_type(4)));

#define DEV __device__ __forceinline__

DEV float bf2f(u16 u){ union{u32 i; float f;} x; x.i = ((u32)u)<<16; return x.f; }
DEV u16 f2bf(float f){ u32 x = __float_as_uint(f); u32 r = (x + 0x7FFFu + ((x>>16)&1u))>>16; return (u16)r; }

DEV f32x4 mfma16(bf16x8 a, bf16x8 b, f32x4 c){
  return __builtin_amdgcn_mfma_f32_16x16x32_bf16(a,b,c,0,0,0);
}
DEV void gload_lds16(const void* g, void* l){
  __builtin_amdgcn_global_load_lds((const __attribute__((address_space(1))) void*)g,
                                   (__attribute__((address_space(3))) void*)l, 16, 0, 0);
}

// ---------------------------------------------------------------- weights: f32 [K][N] -> bf16 [N][K]
__global__ __launch_bounds__(256) void transpose_w(const float* __restrict__ W, u16* __restrict__ Wt,
                                                   int K, int N){
  __shared__ float tile[32][33];
  const int n0 = blockIdx.x*32, k0 = blockIdx.y*32;
  const int tx = threadIdx.x & 31, ty = threadIdx.x >> 5;
  #pragma unroll
  for (int i=0;i<4;++i) tile[ty+8*i][tx] = W[(size_t)(k0+ty+8*i)*N + n0+tx];
  __syncthreads();
  #pragma unroll
  for (int i=0;i<4;++i) Wt[(size_t)(n0+ty+8*i)*K + k0+tx] = f2bf(tile[tx][ty+8*i]);
}

// ---------------------------------------------------------------- LayerNorm: f32 row -> bf16 row (D=1152)
__global__ __launch_bounds__(256) void ln_k(const float* __restrict__ x, const float* __restrict__ gg,
                                            const float* __restrict__ bb, u16* __restrict__ o){
  const int row = blockIdx.x, t = threadIdx.x;
  const float4* xr = (const float4*)(x + (size_t)row*1152);
  float4 v1 = xr[t];
  float s  = v1.x+v1.y+v1.z+v1.w;
  float ss = v1.x*v1.x+v1.y*v1.y+v1.z*v1.z+v1.w*v1.w;
  float4 v2 = {0,0,0,0};
  if (t < 32){ v2 = xr[256+t]; s += v2.x+v2.y+v2.z+v2.w; ss += v2.x*v2.x+v2.y*v2.y+v2.z*v2.z+v2.w*v2.w; }
  #pragma unroll
  for (int off=32; off; off>>=1){ s += __shfl_xor(s,off); ss += __shfl_xor(ss,off); }
  __shared__ float sm[8];
  if ((t&63)==0){ sm[t>>6]=s; sm[4+(t>>6)]=ss; }
  __syncthreads();
  s  = sm[0]+sm[1]+sm[2]+sm[3];
  ss = sm[4]+sm[5]+sm[6]+sm[7];
  const float mu = s*(1.f/1152.f);
  const float var = ss*(1.f/1152.f) - mu*mu;
  const float rs = rsqrtf(var + 1e-5f);
  const float4* g4 = (const float4*)gg; const float4* b4 = (const float4*)bb;
  ushort4* orow = (ushort4*)(o + (size_t)row*1152);
  {
    float4 gv = g4[t], bv = b4[t];
    ushort4 u; u.x=f2bf((v1.x-mu)*rs*gv.x+bv.x); u.y=f2bf((v1.y-mu)*rs*gv.y+bv.y);
               u.z=f2bf((v1.z-mu)*rs*gv.z+bv.z); u.w=f2bf((v1.w-mu)*rs*gv.w+bv.w);
    orow[t] = u;
  }
  if (t < 32){
    float4 gv = g4[256+t], bv = b4[256+t];
    ushort4 u; u.x=f2bf((v2.x-mu)*rs*gv.x+bv.x); u.y=f2bf((v2.y-mu)*rs*gv.y+bv.y);
               u.z=f2bf((v2.z-mu)*rs*gv.z+bv.z); u.w=f2bf((v2.w-mu)*rs*gv.w+bv.w);
    orow[256+t] = u;
  }
}

// ---------------------------------------------------------------- encoder f32 -> bf16, pad 616->640 rows
__global__ void enc_conv(const float* __restrict__ e, u16* __restrict__ ne){
  int i = blockIdx.x*256 + threadIdx.x;           // over 640*288 ushort4-groups
  if (i >= 640*288) return;
  int row = i / 288;
  ushort4 u = {0,0,0,0};
  if (row < 616){ float4 v = ((const float4*)e)[i];
    u.x=f2bf(v.x); u.y=f2bf(v.y); u.z=f2bf(v.z); u.w=f2bf(v.w); }
  ((ushort4*)ne)[i] = u;
}

// ---------------------------------------------------------------- min/max reduce + quantize (bf16 tensors)
__global__ __launch_bounds__(256) void minmax_part(const ushort4* __restrict__ x, int n4, float2* __restrict__ part){
  float mn = 3e38f, mx = -3e38f;
  for (int i = blockIdx.x*256 + threadIdx.x; i < n4; i += gridDim.x*256){
    ushort4 u = x[i];
    float a=bf2f(u.x), b=bf2f(u.y), c=bf2f(u.z), d=bf2f(u.w);
    mn = fminf(mn, fminf(fminf(a,b),fminf(c,d)));
    mx = fmaxf(mx, fmaxf(fmaxf(a,b),fmaxf(c,d)));
  }
  #pragma unroll
  for (int off=32; off; off>>=1){ mn=fminf(mn,__shfl_xor(mn,off)); mx=fmaxf(mx,__shfl_xor(mx,off)); }
  __shared__ float smn[4], smx[4];
  if ((threadIdx.x&63)==0){ smn[threadIdx.x>>6]=mn; smx[threadIdx.x>>6]=mx; }
  __syncthreads();
  if (threadIdx.x==0){
    mn = fminf(fminf(smn[0],smn[1]),fminf(smn[2],smn[3]));
    mx = fmaxf(fmaxf(smx[0],smx[1]),fmaxf(smx[2],smx[3]));
    part[blockIdx.x] = make_float2(mn,mx);
  }
}
__global__ __launch_bounds__(256) void minmax_final(const float2* __restrict__ part, int np, float* __restrict__ prm){
  float mn = 3e38f, mx = -3e38f;
  for (int i = threadIdx.x; i < np; i += 256){ mn=fminf(mn,part[i].x); mx=fmaxf(mx,part[i].y); }
  #pragma unroll
  for (int off=32; off; off>>=1){ mn=fminf(mn,__shfl_xor(mn,off)); mx=fmaxf(mx,__shfl_xor(mx,off)); }
  __shared__ float smn[4], smx[4];
  if ((threadIdx.x&63)==0){ smn[threadIdx.x>>6]=mn; smx[threadIdx.x>>6]=mx; }
  __syncthreads();
  if (threadIdx.x==0){
    mn = fminf(fminf(smn[0],smn[1]),fminf(smn[2],smn[3]));
    mx = fmaxf(fmaxf(smx[0],smx[1]),fmaxf(smx[2],smx[3]));
    float d = (mx-mn)*(1.f/255.f);
    if (!(d > 0.f)) d = 1e-8f;
    prm[0] = d; prm[1] = rintf(-mn/d);
  }
}
__global__ __launch_bounds__(256) void quant_ip(ushort4* __restrict__ x, int n4, const float* __restrict__ prm){
  const float d = prm[0], zp = prm[1];
  for (int i = blockIdx.x*256 + threadIdx.x; i < n4; i += gridDim.x*256){
    ushort4 u = x[i];
    float a=bf2f(u.x), b=bf2f(u.y), c=bf2f(u.z), e=bf2f(u.w);
    a = (fminf(fmaxf(rintf(a/d)+zp,0.f),255.f)-zp)*d;
    b = (fminf(fmaxf(rintf(b/d)+zp,0.f),255.f)-zp)*d;
    c = (fminf(fmaxf(rintf(c/d)+zp,0.f),255.f)-zp)*d;
    e = (fminf(fmaxf(rintf(e/d)+zp,0.f),255.f)-zp)*d;
    u.x=f2bf(a); u.y=f2bf(b); u.z=f2bf(c); u.w=f2bf(e);
    x[i]=u;
  }
}

// ---------------------------------------------------------------- min(l) -> delta_p
__global__ __launch_bounds__(256) void lmin_part(const float4* __restrict__ l4, int n4, float* __restrict__ part){
  float mn = 3e38f;
  for (int i = blockIdx.x*256+threadIdx.x; i<n4; i+=gridDim.x*256){
    float4 v = l4[i];
    mn = fminf(mn, fminf(fminf(v.x,v.y), fminf(v.z,v.w)));
  }
  #pragma unroll
  for (int off=32; off; off>>=1) mn = fminf(mn, __shfl_xor(mn, off));
  __shared__ float sm[4];
  if ((threadIdx.x&63)==0) sm[threadIdx.x>>6] = mn;
  __syncthreads();
  if (threadIdx.x==0) part[blockIdx.x] = fminf(fminf(sm[0],sm[1]),fminf(sm[2],sm[3]));
}
__global__ __launch_bounds__(256) void lmin_final(const float* __restrict__ part, int np, float* __restrict__ prm){
  float mn = 3e38f;
  for (int i = threadIdx.x; i<np; i+=256) mn = fminf(mn, part[i]);
  #pragma unroll
  for (int off=32; off; off>>=1) mn = fminf(mn, __shfl_xor(mn, off));
  __shared__ float sm[4];
  if ((threadIdx.x&63)==0) sm[threadIdx.x>>6] = mn;
  __syncthreads();
  if (threadIdx.x==0){
    mn = fminf(fminf(sm[0],sm[1]),fminf(sm[2],sm[3]));
    float dp = (1.f/mn)*(1.f/255.f);
    prm[0] = dp; prm[1] = 1.f/dp;
  }
}

// ---------------------------------------------------------------- GEMM: C[M,N] = A[M,K](bf16) @ Bt[N,K]^T(bf16)
// EPI 0: C bf16 store ; 1: C bf16 store + bias ; 2: float C += acc + bias
template<int EPI>
__global__ __launch_bounds__(256, 2)
void gemm_bt(const u16* __restrict__ A, const u16* __restrict__ Bt, void* __restrict__ C,
             const float* __restrict__ bias, int K, int ldc){
  __shared__ u16 As[128*64];
  __shared__ u16 Bs[128*64];
  const int t = threadIdx.x;
  const int lane = t & 63, w = t >> 6;
  const int wm = w >> 1, wn = w & 1;
  const int l15 = lane & 15, r16 = (lane >> 4) * 8;
  const int m0 = blockIdx.y * 128, n0 = blockIdx.x * 128;
  const size_t ldaB = (size_t)K * 2;

  f32x4 acc[4][4];
  #pragma unroll
  for (int i=0;i<4;++i)
    #pragma unroll
    for (int j=0;j<4;++j) acc[i][j] = (f32x4){0.f,0.f,0.f,0.f};

  const char* gA = (const char*)A + (size_t)m0 * ldaB;
  const char* gB = (const char*)Bt + (size_t)n0 * ldaB;

  for (int kt = 0; kt < K; kt += 64){
    const size_t kb = (size_t)kt * 2;
    #pragma unroll
    for (int r = 0; r < 4; ++r){
      int li  = r*256 + t;
      int row = li >> 3;
      int cb  = (li & 7) << 4;
      gload_lds16(gA + (size_t)row*ldaB + kb + cb, (char*)As + r*4096 + w*1024);
      gload_lds16(gB + (size_t)row*ldaB + kb + cb, (char*)Bs + r*4096 + w*1024);
    }
    __syncthreads();
    #pragma unroll
    for (int kc = 0; kc < 2; ++kc){
      bf16x8 af[4], bfv[4];
      #pragma unroll
      for (int i=0;i<4;++i) af[i]  = *(const bf16x8*)(As + (wm*64 + i*16 + l15)*64 + kc*32 + r16);
      #pragma unroll
      for (int j=0;j<4;++j) bfv[j] = *(const bf16x8*)(Bs + (wn*64 + j*16 + l15)*64 + kc*32 + r16);
      #pragma unroll
      for (int i=0;i<4;++i)
        #pragma unroll
        for (int j=0;j<4;++j)
          acc[i][j] = mfma16(af[i], bfv[j], acc[i][j]);
    }
    __syncthreads();
  }

  #pragma unroll
  for (int i=0;i<4;++i){
    const int rowb = m0 + wm*64 + i*16 + (lane>>4)*4;
    #pragma unroll
    for (int j=0;j<4;++j){
      const int col = n0 + wn*64 + j*16 + l15;
      float bv = 0.f;
      if (EPI >= 1) bv = bias[col];
      #pragma unroll
      for (int r=0;r<4;++r){
        float v = acc[i][j][r] + bv;
        if (EPI == 2){
          float* H = (float*)C;
          H[(size_t)(rowb + r)*ldc + col] += v;
        } else {
          ((u16*)C)[(size_t)(rowb + r)*ldc + col] = f2bf(v);
        }
      }
    }
  }
}

// ---------------------------------------------------------------- attention passes
// LDS row strides padded to odd multiples of 16B to kill ds_read_b128 bank conflicts:
//   qs/ks: 104 u16 (208B = 13x16B odd) ; vts/ps: 72 u16 (144B = 9x16B odd)
#define QS 104
#define VS 72
// PASSB=0: compute per-row (m, l).  PASSB=1: recompute scores, quantize probs, PV -> out.
template<int PASSB>
__global__ __launch_bounds__(256)
void attn_pass(const u16* __restrict__ qh, const u16* __restrict__ kh, const u16* __restrict__ vh,
               float* __restrict__ mbuf, float* __restrict__ lbuf,
               const float* __restrict__ prmP, u16* __restrict__ outp,
               int SK, int SKT, int kvRowsPerB){
  __shared__ u16 smem[PASSB ? (64*QS*2 + 80*VS + 64*VS) : (64*QS*2)];
  u16* qs  = smem;             // [64][QS]
  u16* ks  = qs + 64*QS;       // [64][QS]
  u16* vts = ks + 64*QS;       // [80][VS]  (PASSB)
  u16* ps  = vts + 80*VS;      // [64][VS]  (PASSB)

  const int t = threadIdx.x;
  const int lane = t & 63, w = t >> 6;
  const int l15 = lane & 15, rg = lane >> 4;
  const int qt = blockIdx.x, bh = blockIdx.y;
  const int b = bh >> 4, h = bh & 15;
  const int q0 = qt * 64;
  const float scale = 0.11785113019775793f;   // 1/sqrt(72)

  const char* qbase = (const char*)qh + ((size_t)(b*1024 + q0)*1152 + h*72)*2;
  const char* kbase = (const char*)kh + ((size_t)((size_t)b*kvRowsPerB)*1152 + h*72)*2;
  const char* vbase = (const char*)vh + ((size_t)((size_t)b*kvRowsPerB)*1152 + h*72)*2;

  for (int li = t; li < 64*52; li += 256){     // stage Q tile (zero-pad head dim 72->104 u16 = 52 u32)
    int row = li/52, cu = li - row*52;
    u32 val = 0;
    if (cu < 36) val = *(const u32*)(qbase + (size_t)row*2304 + cu*4);
    ((u32*)qs)[row*52+cu] = val;
  }
  if (PASSB){
    for (int li = t; li < 8*64; li += 256){    // zero vts pad rows 72..79 (k cols 0..63)
      int rr = li >> 6, cc = li & 63;
      vts[(72+rr)*VS + cc] = 0;
    }
  }

  float mr[4], lr[4], invl[4];
  float dp = 0.f, invdp = 0.f;
  if (PASSB){
    dp = prmP[0]; invdp = prmP[1];
    #pragma unroll
    for (int r=0;r<4;++r){
      int row = q0 + w*16 + rg*4 + r;
      mr[r]   = mbuf[(size_t)bh*1024 + row];
      invl[r] = 1.f / lbuf[(size_t)bh*1024 + row];
    }
  } else {
    #pragma unroll
    for (int r=0;r<4;++r){ mr[r] = -1e30f; lr[r] = 0.f; }
  }

  f32x4 oacc[5];
  if (PASSB){
    #pragma unroll
    for (int cb=0;cb<5;++cb) oacc[cb] = (f32x4){0.f,0.f,0.f,0.f};
  }

  for (int kt = 0; kt < SKT; ++kt){
    if (kt) __syncthreads();
    for (int li = t; li < 64*52; li += 256){   // stage K tile (guard rows >= SK -> 0)
      int row = li/52, cu = li - row*52;
      int krow = kt*64 + row;
      u32 val = 0;
      if (cu < 36 && krow < SK) val = *(const u32*)(kbase + (size_t)krow*2304 + cu*4);
      ((u32*)ks)[row*52+cu] = val;
    }
    if (PASSB){
      for (int li = t; li < 64*36; li += 256){ // stage V transposed [hd][k] (guard rows >= SK -> 0)
        int kr = li/36, hu = li - kr*36;
        int krow = kt*64 + kr;
        u32 val = 0;
        if (krow < SK) val = *(const u32*)(vbase + (size_t)krow*2304 + hu*4);
        vts[(hu*2)*VS + kr]   = (u16)(val & 0xffffu);
        vts[(hu*2+1)*VS + kr] = (u16)(val >> 16);
      }
    }
    __syncthreads();

    f32x4 acc[4];
    #pragma unroll
    for (int cb=0;cb<4;++cb) acc[cb] = (f32x4){0.f,0.f,0.f,0.f};
    #pragma unroll
    for (int kc=0;kc<3;++kc){
      bf16x8 aq = *(const bf16x8*)(qs + (w*16 + l15)*QS + kc*32 + rg*8);
      #pragma unroll
      for (int cb=0;cb<4;++cb){
        bf16x8 bk = *(const bf16x8*)(ks + (cb*16 + l15)*QS + kc*32 + rg*8);
        acc[cb] = mfma16(aq, bk, acc[cb]);
      }
    }
    float s[4][4];
    #pragma unroll
    for (int cb=0;cb<4;++cb){
      const int col = kt*64 + cb*16 + l15;
      const bool valid = col < SK;
      #pragma unroll
      for (int r=0;r<4;++r){
        float x = acc[cb][r]*scale;
        s[cb][r] = valid ? x : -1e30f;
      }
    }
    if (!PASSB){
      #pragma unroll
      for (int r=0;r<4;++r){
        float mt = fmaxf(fmaxf(s[0][r],s[1][r]), fmaxf(s[2][r],s[3][r]));
        #pragma unroll
        for (int off=1; off<16; off<<=1) mt = fmaxf(mt, __shfl_xor(mt, off));
        float mn = fmaxf(mr[r], mt);
        float sum = __expf(s[0][r]-mn)+__expf(s[1][r]-mn)+__expf(s[2][r]-mn)+__expf(s[3][r]-mn);
        #pragma unroll
        for (int off=1; off<16; off<<=1) sum += __shfl_xor(sum, off);
        lr[r] = lr[r]*__expf(mr[r]-mn) + sum;
        mr[r] = mn;
      }
    } else {
      #pragma unroll
      for (int cb=0;cb<4;++cb){
        #pragma unroll
        for (int r=0;r<4;++r){
          float p  = __expf(s[cb][r]-mr[r]) * invl[r];
          float pq = fminf(rintf(p*invdp), 255.f) * dp;
          ps[(w*16 + rg*4 + r)*VS + cb*16 + l15] = f2bf(pq);
        }
      }
      __syncthreads();
      #pragma unroll
      for (int kc=0;kc<2;++kc){
        bf16x8 ap = *(const bf16x8*)(ps + (w*16 + l15)*VS + kc*32 + rg*8);
        #pragma unroll
        for (int cb=0;cb<5;++cb){
          bf16x8 bv = *(const bf16x8*)(vts + (cb*16 + l15)*VS + kc*32 + rg*8);
          oacc[cb] = mfma16(ap, bv, oacc[cb]);
        }
      }
    }
  }

  if (!PASSB){
    if (l15 == 0){
      #pragma unroll
      for (int r=0;r<4;++r){
        int row = q0 + w*16 + rg*4 + r;
        mbuf[(size_t)bh*1024 + row] = mr[r];
        lbuf[(size_t)bh*1024 + row] = lr[r];
      }
    }
  } else {
    #pragma unroll
    for (int cb=0;cb<5;++cb){
      int hd = cb*16 + l15;
      if (hd < 72){
        #pragma unroll
        for (int r=0;r<4;++r){
          int row = q0 + w*16 + rg*4 + r;
          outp[((size_t)(b*1024 + row))*1152 + h*72 + hd] = f2bf(oacc[cb][r]);
        }
      }
    }
  }
}

// ---------------------------------------------------------------- GEGLU elementwise
__global__ __launch_bounds__(256) void geglu_k(const u16* __restrict__ proj, u16* __restrict__ out, int rows){
  const int total = rows*1152;                 // ushort4 groups (4608/4 per row)
  for (int i = blockIdx.x*256+threadIdx.x; i < total; i += gridDim.x*256){
    int row = i / 1152, c4 = i - row*1152;
    ushort4 ua = ((const ushort4*)(proj + (size_t)row*9216))[c4];
    ushort4 ug = ((const ushort4*)(proj + (size_t)row*9216 + 4608))[c4];
    float a0=bf2f(ua.x), a1=bf2f(ua.y), a2=bf2f(ua.z), a3=bf2f(ua.w);
    float g0=bf2f(ug.x), g1=bf2f(ug.y), g2=bf2f(ug.z), g3=bf2f(ug.w);
    const float c = 0.70710678118654752f;
    g0 = 0.5f*g0*(1.f+erff(g0*c)); g1 = 0.5f*g1*(1.f+erff(g1*c));
    g2 = 0.5f*g2*(1.f+erff(g2*c)); g3 = 0.5f*g3*(1.f+erff(g3*c));
    ushort4 u; u.x=f2bf(a0*g0); u.y=f2bf(a1*g1); u.z=f2bf(a2*g2); u.w=f2bf(a3*g3);
    ((ushort4*)(out + (size_t)row*4608))[c4] = u;
  }
}

// ================================================================ launcher
extern "C" void kernel_launch(void* const* d_in, const int* in_sizes, int n_in,
                              void* d_out, int out_size, void* d_ws, size_t ws_size,
                              hipStream_t stream){
  const float* hidden = (const float*)d_in[0];
  const float* enc    = (const float*)d_in[1];
  const float* ln1g = (const float*)d_in[2];  const float* ln1b = (const float*)d_in[3];
  const float* Wq1 = (const float*)d_in[4];   const float* Wk1 = (const float*)d_in[5];
  const float* Wv1 = (const float*)d_in[6];   const float* Wo1 = (const float*)d_in[7];
  const float* bo1 = (const float*)d_in[8];
  const float* ln2g = (const float*)d_in[9];  const float* ln2b = (const float*)d_in[10];
  const float* Wq2 = (const float*)d_in[11];  const float* Wk2 = (const float*)d_in[12];
  const float* Wv2 = (const float*)d_in[13];  const float* Wo2 = (const float*)d_in[14];
  const float* bo2 = (const float*)d_in[15];
  const float* ln3g = (const float*)d_in[16]; const float* ln3b = (const float*)d_in[17];
  const float* Wff1 = (const float*)d_in[18]; const float* bff1 = (const float*)d_in[19];
  const float* Wff2 = (const float*)d_in[20]; const float* bff2 = (const float*)d_in[21];

  // d_out IS the f32 residual accumulator Hf: [8192][1152] f32 = 37,748,736 B
  float* Hf = (float*)d_out;

  char* ws = (char*)d_ws;
  // ---- compact layout, high-water ~80.7 MB ----
  u16*  Nb   = (u16*)(ws + 0);                //  18,874,368  bf16 [8192][1152]
  u16*  Qb   = (u16*)(ws + 18874368);         //  18,874,368
  u16*  Kb   = (u16*)(ws + 37748736);         //  18,874,368
  u16*  Vb   = (u16*)(ws + 56623104);         //  18,874,368  (ends 75,497,472)
  u16*  NE   = (u16*)(ws + 75497472);         //   1,474,560  bf16 [640][1152]
  float* Mb  = (float*)(ws + 76972032);       //     524,288
  float* Lb  = (float*)(ws + 77496320);       //     524,288
  float2* Part = (float2*)(ws + 78020608);    //      16,384
  float* PartF = (float*)(ws + 78020608);
  float* Prm = (float*)(ws + 78036992);       //         256
  u16*  Wsl  = (u16*)(ws + 78037248);         //   2,654,208  rotating attn weight slot (ends 80,691,456)
  // FF-phase overlay (Qb/Kb/Vb/NE/Mb/Lb/Part/Prm/Wsl all dead by then)
  u16*  Wff1t = (u16*)(ws + 18874368);        //  21,233,664
  u16*  Wff2t = (u16*)(ws + 40108032);        //  10,616,832
  u16*  PROJ  = (u16*)(ws + 50724864);        //  18,874,368  bf16 [1024][9216]
  u16*  GEG   = (u16*)(ws + 69599232);        //   9,437,184  bf16 [1024][4608] (ends 79,036,416)

  const int NT = 8192;                // tokens
  const int NQ4 = NT*1152/4;          // 2,359,296 ushort4 in a [8192,1152] bf16 buffer

  hipMemcpyAsync(Hf, hidden, (size_t)NT*1152*4, hipMemcpyDeviceToDevice, stream);
  enc_conv<<<720,256,0,stream>>>(enc, NE);

  // ---------------- self-attention ----------------
  ln_k<<<NT,256,0,stream>>>(Hf, ln1g, ln1b, Nb);
  transpose_w<<<dim3(36,36),256,0,stream>>>(Wq1, Wsl, 1152, 1152);
  gemm_bt<0><<<dim3(9,64),256,0,stream>>>(Nb, Wsl, Qb, nullptr, 1152, 1152);
  transpose_w<<<dim3(36,36),256,0,stream>>>(Wk1, Wsl, 1152, 1152);
  gemm_bt<0><<<dim3(9,64),256,0,stream>>>(Nb, Wsl, Kb, nullptr, 1152, 1152);
  transpose_w<<<dim3(36,36),256,0,stream>>>(Wv1, Wsl, 1152, 1152);
  gemm_bt<0><<<dim3(9,64),256,0,stream>>>(Nb, Wsl, Vb, nullptr, 1152, 1152);

  minmax_part<<<1024,256,0,stream>>>((ushort4*)Qb, NQ4, Part);
  minmax_final<<<1,256,0,stream>>>(Part, 1024, Prm+0);
  quant_ip<<<2048,256,0,stream>>>((ushort4*)Qb, NQ4, Prm+0);
  minmax_part<<<1024,256,0,stream>>>((ushort4*)Kb, NQ4, Part);
  minmax_final<<<1,256,0,stream>>>(Part, 1024, Prm+2);
  quant_ip<<<2048,256,0,stream>>>((ushort4*)Kb, NQ4, Prm+2);
  minmax_part<<<1024,256,0,stream>>>((ushort4*)Vb, NQ4, Part);
  minmax_final<<<1,256,0,stream>>>(Part, 1024, Prm+4);
  quant_ip<<<2048,256,0,stream>>>((ushort4*)Vb, NQ4, Prm+4);

  attn_pass<0><<<dim3(16,128),256,0,stream>>>(Qb,Kb,nullptr, Mb,Lb, nullptr,nullptr, 1024,16,1024);
  lmin_part<<<64,256,0,stream>>>((const float4*)Lb, 32768, PartF);
  lmin_final<<<1,256,0,stream>>>(PartF, 64, Prm+6);
  attn_pass<1><<<dim3(16,128),256,0,stream>>>(Qb,Kb,Vb, Mb,Lb, Prm+6, Nb, 1024,16,1024);
  transpose_w<<<dim3(36,36),256,0,stream>>>(Wo1, Wsl, 1152, 1152);
  gemm_bt<2><<<dim3(9,64),256,0,stream>>>(Nb, Wsl, Hf, bo1, 1152, 1152);

  // ---------------- cross-attention ----------------
  ln_k<<<NT,256,0,stream>>>(Hf, ln2g, ln2b, Nb);
  transpose_w<<<dim3(36,36),256,0,stream>>>(Wq2, Wsl, 1152, 1152);
  gemm_bt<0><<<dim3(9,64),256,0,stream>>>(Nb, Wsl, Qb, nullptr, 1152, 1152);
  transpose_w<<<dim3(36,36),256,0,stream>>>(Wk2, Wsl, 1152, 1152);
  gemm_bt<0><<<dim3(9,5),256,0,stream>>>(NE, Wsl, Kb, nullptr, 1152, 1152);
  transpose_w<<<dim3(36,36),256,0,stream>>>(Wv2, Wsl, 1152, 1152);
  gemm_bt<0><<<dim3(9,5),256,0,stream>>>(NE, Wsl, Vb, nullptr, 1152, 1152);

  const int NK4r = 616*1152/4;  // real encoder rows only for calibration
  const int NK4c = 640*1152/4;  // quantize incl. zero pad rows (0 -> 0)
  minmax_part<<<1024,256,0,stream>>>((ushort4*)Qb, NQ4, Part);
  minmax_final<<<1,256,0,stream>>>(Part, 1024, Prm+0);
  quant_ip<<<2048,256,0,stream>>>((ushort4*)Qb, NQ4, Prm+0);
  minmax_part<<<512,256,0,stream>>>((ushort4*)Kb, NK4r, Part);
  minmax_final<<<1,256,0,stream>>>(Part, 512, Prm+2);
  quant_ip<<<512,256,0,stream>>>((ushort4*)Kb, NK4c, Prm+2);
  minmax_part<<<512,256,0,stream>>>((ushort4*)Vb, NK4r, Part);
  minmax_final<<<1,256,0,stream>>>(Part, 512, Prm+4);
  quant_ip<<<512,256,0,stream>>>((ushort4*)Vb, NK4c, Prm+4);

  attn_pass<0><<<dim3(16,128),256,0,stream>>>(Qb,Kb,nullptr, Mb,Lb, nullptr,nullptr, 77,2,77);
  lmin_part<<<64,256,0,stream>>>((const float4*)Lb, 32768, PartF);
  lmin_final<<<1,256,0,stream>>>(PartF, 64, Prm+6);
  attn_pass<1><<<dim3(16,128),256,0,stream>>>(Qb,Kb,Vb, Mb,Lb, Prm+6, Nb, 77,2,77);
  transpose_w<<<dim3(36,36),256,0,stream>>>(Wo2, Wsl, 1152, 1152);
  gemm_bt<2><<<dim3(9,64),256,0,stream>>>(Nb, Wsl, Hf, bo2, 1152, 1152);

  // ---------------- feed-forward (GEGLU), 8 chunks of 1024 rows ----------------
  ln_k<<<NT,256,0,stream>>>(Hf, ln3g, ln3b, Nb);
  transpose_w<<<dim3(288,36),256,0,stream>>>(Wff1, Wff1t, 1152, 9216);
  transpose_w<<<dim3(36,144),256,0,stream>>>(Wff2, Wff2t, 4608, 1152);
  for (int c = 0; c < 8; ++c){
    gemm_bt<1><<<dim3(72,8),256,0,stream>>>(Nb + (size_t)c*1024*1152, Wff1t, PROJ, bff1, 1152, 9216);
    geglu_k<<<1024,256,0,stream>>>(PROJ, GEG, 1024);
    gemm_bt<2><<<dim3(9,8),256,0,stream>>>(GEG, Wff2t, Hf + (size_t)c*1024*1152, bff2, 4608, 1152);
  }
}